// Round 1
// baseline (341.089 us; speedup 1.0000x reference)
//
#include <hip/hip_runtime.h>

#define VOCAB   32000
#define EMB_DIM 2048
#define N_COMP  64
#define SEQ_L   128
#define BATCH   4096

// ---------------------------------------------------------------------------
// Kernel 1: S[n][d] = sum_t emb[ids[n][t]][d]   (mean scale folded into mix)
// grid (64 components, 2 col-chunks of 1024, 4 token-chunks of 32), block 256.
// Each thread owns 4 contiguous cols (float4). Token-split + atomicAdd gives
// 512 blocks (~8 waves/CU) so enough loads are in flight to reach HBM BW.
// ---------------------------------------------------------------------------
__global__ __launch_bounds__(256) void gather_sum(
    const int* __restrict__ ids,
    const float* __restrict__ emb,
    float* __restrict__ S) {
  const int n   = blockIdx.x;
  const int col = blockIdx.y * 1024 + threadIdx.x * 4;
  const int t0  = blockIdx.z * 32;

  float4 acc = make_float4(0.f, 0.f, 0.f, 0.f);
  const int* idp = ids + n * SEQ_L + t0;

#pragma unroll 8
  for (int t = 0; t < 32; ++t) {
    const int id = idp[t];  // wave-uniform -> s_load
    const float4 v = *(const float4*)(emb + (size_t)id * EMB_DIM + col);
    acc.x += v.x; acc.y += v.y; acc.z += v.z; acc.w += v.w;
  }

  float* o = S + n * EMB_DIM + col;
  atomicAdd(o + 0, acc.x);
  atomicAdd(o + 1, acc.y);
  atomicAdd(o + 2, acc.z);
  atomicAdd(o + 3, acc.w);
}

// ---------------------------------------------------------------------------
// Kernel 2: out[b][d] = (1/128) * sum_n ratio[b][n] * S[n][d]
// grid (4096/16 rows, 2 col-chunks of 1024), block 256.
// Each thread: 16 rows x 4 cols accumulator (64 VGPRs). ratio index is
// wave-uniform -> scalar loads; S is 512 KB, L2-resident.
// ---------------------------------------------------------------------------
__global__ __launch_bounds__(256) void mix(
    const float* __restrict__ ratio,
    const float* __restrict__ S,
    float* __restrict__ out) {
  const int row0 = blockIdx.x * 16;
  const int col  = blockIdx.y * 1024 + threadIdx.x * 4;

  float4 acc[16];
#pragma unroll
  for (int r = 0; r < 16; ++r) acc[r] = make_float4(0.f, 0.f, 0.f, 0.f);

#pragma unroll 4
  for (int n = 0; n < N_COMP; ++n) {
    const float4 p = *(const float4*)(S + n * EMB_DIM + col);
#pragma unroll
    for (int r = 0; r < 16; ++r) {
      const float s = ratio[(row0 + r) * N_COMP + n];  // uniform -> s_load
      acc[r].x += s * p.x;
      acc[r].y += s * p.y;
      acc[r].z += s * p.z;
      acc[r].w += s * p.w;
    }
  }

  const float inv = 1.0f / (float)SEQ_L;
#pragma unroll
  for (int r = 0; r < 16; ++r) {
    float4 o;
    o.x = acc[r].x * inv; o.y = acc[r].y * inv;
    o.z = acc[r].z * inv; o.w = acc[r].w * inv;
    *(float4*)(out + (size_t)(row0 + r) * EMB_DIM + col) = o;
  }
}

extern "C" void kernel_launch(void* const* d_in, const int* in_sizes, int n_in,
                              void* d_out, int out_size, void* d_ws, size_t ws_size,
                              hipStream_t stream) {
  const int*   ids   = (const int*)d_in[0];    // [64,128] int32
  const float* ratio = (const float*)d_in[1];  // [4096,64] f32
  const float* emb   = (const float*)d_in[2];  // [32000,2048] f32
  float* out = (float*)d_out;                  // [4096,2048] f32
  float* S   = (float*)d_ws;                   // [64,2048] f32 partial sums

  // d_ws is poisoned 0xAA before every timed launch -> must zero for atomics.
  hipMemsetAsync(S, 0, (size_t)N_COMP * EMB_DIM * sizeof(float), stream);

  gather_sum<<<dim3(N_COMP, 2, 4), 256, 0, stream>>>(ids, emb, S);
  mix<<<dim3(BATCH / 16, 2), 256, 0, stream>>>(ratio, S, out);
}

// Round 2
// 331.222 us; speedup vs baseline: 1.0298x; 1.0298x over previous
//
#include <hip/hip_runtime.h>

#define VOCAB   32000
#define EMB_DIM 2048
#define N_COMP  64
#define SEQ_L   128
#define BATCH   4096

// ---------------------------------------------------------------------------
// Kernel 1: S[n][c] = (1/SEQ_L) * sum_t emb[ids[n][t]][c]
// grid (64 comp, 8 col-chunks of 256), block 256 = 4 waves.
// Wave w sums tokens [w*32, w*32+32) over its 256-col chunk (float4/lane),
// then a conflict-free LDS reduce across the 4 waves. No atomics, no memset.
// Full unroll -> 32 independent float4 loads in flight per wave.
// ---------------------------------------------------------------------------
__global__ __launch_bounds__(256) void gather_pool(
    const int* __restrict__ ids,
    const float* __restrict__ emb,
    float* __restrict__ S) {
  const int n     = blockIdx.x;
  const int chunk = blockIdx.y;            // 0..7
  const int tid   = threadIdx.x;
  const int w     = tid >> 6;              // wave 0..3
  const int lane  = tid & 63;
  const int col   = chunk * 256 + lane * 4;

  const int* idp = ids + n * SEQ_L + w * 32;

  float4 acc = make_float4(0.f, 0.f, 0.f, 0.f);
#pragma unroll
  for (int t = 0; t < 32; ++t) {
    const int id = idp[t];                 // block-uniform
    const float4 v = *(const float4*)(emb + (size_t)id * EMB_DIM + col);
    acc.x += v.x; acc.y += v.y; acc.z += v.z; acc.w += v.w;
  }

  __shared__ float red[4 * 256];           // 4 KB
  *(float4*)(red + w * 256 + lane * 4) = acc;  // stride-16B b128: conflict-free
  __syncthreads();

  // thread i reduces column (chunk*256 + i) across the 4 wave partials.
  const float s = red[tid] + red[256 + tid] + red[512 + tid] + red[768 + tid];
  S[n * EMB_DIM + chunk * 256 + tid] = s * (1.0f / (float)SEQ_L);
}

// ---------------------------------------------------------------------------
// Kernel 2: out[b][d] = sum_n ratio[b][n] * S[n][d]   (mean already folded)
// grid (4096/16, 2 col-chunks of 1024), block 256.
// 16 rows x float4 accumulator per thread; ratio index is block-uniform ->
// scalar loads; S (512 KB) is L2/LLC-resident.
// ---------------------------------------------------------------------------
__global__ __launch_bounds__(256) void mix(
    const float* __restrict__ ratio,
    const float* __restrict__ S,
    float* __restrict__ out) {
  const int row0 = blockIdx.x * 16;
  const int col  = blockIdx.y * 1024 + threadIdx.x * 4;

  float4 acc[16];
#pragma unroll
  for (int r = 0; r < 16; ++r) acc[r] = make_float4(0.f, 0.f, 0.f, 0.f);

#pragma unroll 8
  for (int n = 0; n < N_COMP; ++n) {
    const float4 p = *(const float4*)(S + n * EMB_DIM + col);
#pragma unroll
    for (int r = 0; r < 16; ++r) {
      const float s = ratio[(row0 + r) * N_COMP + n];  // uniform -> s_load
      acc[r].x += s * p.x;
      acc[r].y += s * p.y;
      acc[r].z += s * p.z;
      acc[r].w += s * p.w;
    }
  }

#pragma unroll
  for (int r = 0; r < 16; ++r) {
    *(float4*)(out + (size_t)(row0 + r) * EMB_DIM + col) = acc[r];
  }
}

extern "C" void kernel_launch(void* const* d_in, const int* in_sizes, int n_in,
                              void* d_out, int out_size, void* d_ws, size_t ws_size,
                              hipStream_t stream) {
  const int*   ids   = (const int*)d_in[0];    // [64,128] int32
  const float* ratio = (const float*)d_in[1];  // [4096,64] f32
  const float* emb   = (const float*)d_in[2];  // [32000,2048] f32
  float* out = (float*)d_out;                  // [4096,2048] f32
  float* S   = (float*)d_ws;                   // [64,2048] f32 pooled

  gather_pool<<<dim3(N_COMP, EMB_DIM / 256), 256, 0, stream>>>(ids, emb, S);
  mix<<<dim3(BATCH / 16, 2), 256, 0, stream>>>(ratio, S, out);
}